// Round 1
// baseline (157.386 us; speedup 1.0000x reference)
//
#include <hip/hip_runtime.h>

#define NROWS  32768
#define DIM    64
#define KCODES 1024
#define NELEM  (NROWS * DIM)   // 2097152

// numpy-style pairwise sum of squares for n=64 contiguous fp32:
// sq[i] = fl(v[i]^2) elementwise, then the 8-accumulator unrolled pairwise
// reduction ((r0+r1)+(r2+r3))+((r4+r5)+(r6+r7)). Contraction OFF so hipcc's
// default -ffp-contract=fast cannot fuse v*v into the add (numpy computes the
// squared temp array first, then sums).
__device__ __forceinline__ float np_sumsq64(const float v[64]) {
#pragma clang fp contract(off)
  float r0 = v[0] * v[0];
  float r1 = v[1] * v[1];
  float r2 = v[2] * v[2];
  float r3 = v[3] * v[3];
  float r4 = v[4] * v[4];
  float r5 = v[5] * v[5];
  float r6 = v[6] * v[6];
  float r7 = v[7] * v[7];
#pragma unroll
  for (int i = 8; i < 64; i += 8) {
    r0 += v[i + 0] * v[i + 0];
    r1 += v[i + 1] * v[i + 1];
    r2 += v[i + 2] * v[i + 2];
    r3 += v[i + 3] * v[i + 3];
    r4 += v[i + 4] * v[i + 4];
    r5 += v[i + 5] * v[i + 5];
    r6 += v[i + 6] * v[i + 6];
    r7 += v[i + 7] * v[i + 7];
  }
  return ((r0 + r1) + (r2 + r3)) + ((r4 + r5) + (r6 + r7));
}

// Phase 1: per-code ||e||^2 (same numpy pairwise rounding) + zero the loss slot.
__global__ void vq_prep(const float* __restrict__ w, float* __restrict__ se,
                        double* __restrict__ loss) {
  int c = blockIdx.x * 256 + threadIdx.x;
  if (c == 0) *loss = 0.0;
  if (c < KCODES) {
    float v[64];
    const float4* wr = (const float4*)(w + (size_t)c * DIM);
#pragma unroll
    for (int i = 0; i < 16; ++i) {
      float4 t = wr[i];
      v[4 * i + 0] = t.x; v[4 * i + 1] = t.y;
      v[4 * i + 2] = t.z; v[4 * i + 3] = t.w;
    }
    se[c] = np_sumsq64(v);
  }
}

// Phase 2: distances + per-chunk argmin.
// Grid 512 blocks x 256 threads: block = (row_group g = blockIdx>>2) x (K-chunk
// chunk = blockIdx&3). Thread owns one row: x[64] lives in VGPRs; the codebook
// stream is wave-uniform (address depends only on uniform loop vars) so it can
// go through the scalar/uniform load path instead of the LDS port.
// d = fl(fl(Sx + Se[c]) - 2*dot)  — note fl(2*dot) is exact, so an FMA
// contraction of (a - 2*dot) is bit-identical to the ref's separate ops.
// Argmin with lowest-index tie-break: distances are positive (>= min chi^2_64
// ~ 20), so the fp32 bit pattern is monotone; pack (dist_bits<<32)|c and take
// the u64 min.
__global__ __launch_bounds__(256) void vq_dist(const float* __restrict__ x,
                                               const float* __restrict__ w,
                                               const float* __restrict__ se,
                                               unsigned long long* __restrict__ keys) {
  const int g = blockIdx.x >> 2;
  const int chunk = blockIdx.x & 3;
  const int row = g * 256 + threadIdx.x;

  float xv[64];
  const float4* xr = (const float4*)(x + (size_t)row * DIM);
#pragma unroll
  for (int i = 0; i < 16; ++i) {
    float4 t = xr[i];
    xv[4 * i + 0] = t.x; xv[4 * i + 1] = t.y;
    xv[4 * i + 2] = t.z; xv[4 * i + 3] = t.w;
  }
  const float sx = np_sumsq64(xv);

  const int c0 = chunk * 256;
  const float4* w4 = (const float4*)w;
  unsigned long long best = 0xFFFFFFFFFFFFFFFFull;

#pragma unroll 2
  for (int j = 0; j < 256; ++j) {
    const int c = c0 + j;
    const float4* wr = w4 + (size_t)c * 16;
    float a0 = 0.f, a1 = 0.f, a2 = 0.f, a3 = 0.f;
#pragma unroll
    for (int i = 0; i < 16; ++i) {
      float4 t = wr[i];
      a0 += t.x * xv[4 * i + 0];
      a1 += t.y * xv[4 * i + 1];
      a2 += t.z * xv[4 * i + 2];
      a3 += t.w * xv[4 * i + 3];
    }
    float dot = (a0 + a1) + (a2 + a3);
    float ad = sx + se[c];        // fl(Sx + Se)  (broadcast add in the ref)
    float d  = ad - 2.0f * dot;   // fl(ad - 2*dot); fl(2*dot) exact
    unsigned long long key =
        ((unsigned long long)__float_as_uint(d) << 32) | (unsigned long long)c;
    if (key < best) best = key;
  }
  keys[(size_t)row * 4 + chunk] = best;
}

// Phase 3: combine the 4 K-chunk keys per row -> index; write indices (as
// float), the straight-through quantized output x + fl(w - x) (bit-exact
// replication of the ref's forward value), and accumulate the fp64 loss sum.
__global__ __launch_bounds__(256) void vq_out(const float* __restrict__ x,
                                              const float* __restrict__ w,
                                              const unsigned long long* __restrict__ keys,
                                              float* __restrict__ outq,
                                              float* __restrict__ outidx,
                                              double* __restrict__ loss) {
  __shared__ int sidx[256];
  __shared__ double red[256];
  const int b = blockIdx.x, t = threadIdx.x;
  const int row = b * 256 + t;

  const unsigned long long* kr = keys + (size_t)row * 4;
  unsigned long long k0 = kr[0], k1 = kr[1], k2 = kr[2], k3 = kr[3];
  unsigned long long kmin = k0 < k1 ? k0 : k1;
  unsigned long long kmin2 = k2 < k3 ? k2 : k3;
  if (kmin2 < kmin) kmin = kmin2;
  const int idx = (int)(kmin & 0xFFFFFFFFull);
  outidx[row] = (float)idx;
  sidx[t] = idx;
  __syncthreads();

  double acc = 0.0;
  const float4* x4 = (const float4*)x;
  float4* o4 = (float4*)outq;
#pragma unroll
  for (int i = 0; i < 16; ++i) {
    const int e  = i * 256 + t;     // 0..4095 float4s of this block's 256 rows
    const int rl = e >> 4;          // local row
    const int d4 = e & 15;          // float4 within the row
    const size_t gofs = (size_t)(b * 256 + rl) * 16 + d4;
    float4 xvv = x4[gofs];
    const float4* wr = (const float4*)(w + (size_t)sidx[rl] * DIM);
    float4 wv = wr[d4];
    float tx = wv.x - xvv.x, ty = wv.y - xvv.y;
    float tz = wv.z - xvv.z, tw = wv.w - xvv.w;
    float4 q;
    q.x = xvv.x + tx; q.y = xvv.y + ty;   // ref STE: x + fl(q - x)
    q.z = xvv.z + tz; q.w = xvv.w + tw;
    o4[gofs] = q;
    acc += (double)tx * tx + (double)ty * ty + (double)tz * tz + (double)tw * tw;
  }

  red[t] = acc;
  __syncthreads();
  for (int s = 128; s > 0; s >>= 1) {
    if (t < s) red[t] += red[t + s];
    __syncthreads();
  }
  if (t == 0) atomicAdd(loss, red[0]);
}

// Phase 4: commitment = 0.25*(q_loss + e_loss) = 0.5 * mean  (q==e numerically)
__global__ void vq_fin(const double* __restrict__ loss, float* __restrict__ outloss) {
  float m = (float)(*loss / (double)NELEM);
  *outloss = 0.5f * m;
}

extern "C" void kernel_launch(void* const* d_in, const int* in_sizes, int n_in,
                              void* d_out, int out_size, void* d_ws, size_t ws_size,
                              hipStream_t stream) {
  const float* x = (const float*)d_in[0];   // inputs (32,64,32,32) fp32
  const float* w = (const float*)d_in[1];   // weight (1024,64) fp32

  float* outq    = (float*)d_out;           // [0, 2097152)
  float* outidx  = outq + NELEM;            // [2097152, +32768)
  float* outloss = outidx + NROWS;          // [2129920]

  char* wsb = (char*)d_ws;
  double* loss = (double*)wsb;                              // 8 B
  float* se = (float*)(wsb + 256);                          // 4 KB
  unsigned long long* keys = (unsigned long long*)(wsb + 8192);  // 1 MB

  hipLaunchKernelGGL(vq_prep, dim3(4),   dim3(256), 0, stream, w, se, loss);
  hipLaunchKernelGGL(vq_dist, dim3(512), dim3(256), 0, stream, x, w, se, keys);
  hipLaunchKernelGGL(vq_out,  dim3(128), dim3(256), 0, stream, x, w, keys, outq, outidx, loss);
  hipLaunchKernelGGL(vq_fin,  dim3(1),   dim3(1),   0, stream, loss, outloss);
}

// Round 2
// 130.153 us; speedup vs baseline: 1.2092x; 1.2092x over previous
//
#include <hip/hip_runtime.h>

#define NROWS  32768
#define DIM    64
#define KCODES 1024
#define NELEM  (NROWS * DIM)   // 2097152

typedef float v2f __attribute__((ext_vector_type(2)));

// numpy-style pairwise sum of squares for n=64 contiguous fp32:
// sq[i] = fl(v[i]^2) elementwise, then the 8-accumulator unrolled pairwise
// reduction ((r0+r1)+(r2+r3))+((r4+r5)+(r6+r7)). Contraction OFF so hipcc's
// default -ffp-contract=fast cannot fuse v*v into the add (numpy computes the
// squared temp array first, then sums). Verified round 1: absmax 0.0.
__device__ __forceinline__ float np_sumsq64(const float v[64]) {
#pragma clang fp contract(off)
  float r0 = v[0] * v[0];
  float r1 = v[1] * v[1];
  float r2 = v[2] * v[2];
  float r3 = v[3] * v[3];
  float r4 = v[4] * v[4];
  float r5 = v[5] * v[5];
  float r6 = v[6] * v[6];
  float r7 = v[7] * v[7];
#pragma unroll
  for (int i = 8; i < 64; i += 8) {
    r0 += v[i + 0] * v[i + 0];
    r1 += v[i + 1] * v[i + 1];
    r2 += v[i + 2] * v[i + 2];
    r3 += v[i + 3] * v[i + 3];
    r4 += v[i + 4] * v[i + 4];
    r5 += v[i + 5] * v[i + 5];
    r6 += v[i + 6] * v[i + 6];
    r7 += v[i + 7] * v[i + 7];
  }
  return ((r0 + r1) + (r2 + r3)) + ((r4 + r5) + (r6 + r7));
}

// Phase 1 (grid 128x256, one thread per row): init keys to +inf, per-row
// ||x||^2, per-code ||e||^2 (first 1024 threads), zero loss slot.
__global__ __launch_bounds__(256) void vq_prep(const float* __restrict__ x,
                                               const float* __restrict__ w,
                                               float* __restrict__ se,
                                               float* __restrict__ sxv,
                                               unsigned long long* __restrict__ keys,
                                               double* __restrict__ loss) {
  const int t = blockIdx.x * 256 + threadIdx.x;  // 0..32767
  if (t == 0) *loss = 0.0;
  keys[t] = ~0ull;

  float v[64];
  const float4* xr = (const float4*)(x + (size_t)t * DIM);
#pragma unroll
  for (int i = 0; i < 16; ++i) {
    float4 q = xr[i];
    v[4 * i + 0] = q.x; v[4 * i + 1] = q.y;
    v[4 * i + 2] = q.z; v[4 * i + 3] = q.w;
  }
  sxv[t] = np_sumsq64(v);

  if (t < KCODES) {
    const float4* wr = (const float4*)(w + (size_t)t * DIM);
#pragma unroll
    for (int i = 0; i < 16; ++i) {
      float4 q = wr[i];
      v[4 * i + 0] = q.x; v[4 * i + 1] = q.y;
      v[4 * i + 2] = q.z; v[4 * i + 3] = q.w;
    }
    se[t] = np_sumsq64(v);
  }
}

// Phase 2: distances + argmin via u64-key atomicMin.
// Grid 1024 = 128 row-groups x 8 K-chunks -> 4096 waves (4 blocks/CU at 4
// waves/SIMD, matching the 128-VGPR budget from __launch_bounds__(256,4)).
// Thread owns one row: xv[64] resident in VGPRs (the whole point of the
// (256,4) bound — round 1's 40-VGPR allocation forced in-loop x reloads).
// w addresses are wave-uniform -> scalar-load path (SGPR file), so VALU issue
// is ~32 v_pk_fma_f32 + ~10 misc per code.
// d = fma(-2, dot, fl(sx+se[c])) — bit-identical to ref's fl(fl(sx+se)-fl(2dot))
// since fl(2*dot) is exact. Distances positive -> fp32 bits monotone -> pack
// (dist_bits<<32)|c, u64 min = argmin with lowest-index tie-break.
__global__ __launch_bounds__(256, 4) void vq_dist(const float* __restrict__ x,
                                                  const float* __restrict__ w,
                                                  const float* __restrict__ se,
                                                  const float* __restrict__ sxv,
                                                  unsigned long long* __restrict__ keys) {
  const int g = blockIdx.x >> 3;
  const int chunk = blockIdx.x & 7;
  const int row = g * 256 + threadIdx.x;

  v2f xv[32];
  const float4* xr = (const float4*)(x + (size_t)row * DIM);
#pragma unroll
  for (int i = 0; i < 16; ++i) {
    float4 t = xr[i];
    xv[2 * i + 0] = (v2f){t.x, t.y};
    xv[2 * i + 1] = (v2f){t.z, t.w};
  }
  const float sx = sxv[row];

  const int c0 = chunk * 128;
  const float4* w4 = (const float4*)w;
  unsigned long long best = ~0ull;

#pragma unroll 2
  for (int j = 0; j < 128; ++j) {
    const int c = c0 + j;
    const float4* wr = w4 + (size_t)c * 16;
    v2f a0 = (v2f){0.f, 0.f}, a1 = (v2f){0.f, 0.f};
    v2f a2 = (v2f){0.f, 0.f}, a3 = (v2f){0.f, 0.f};
#pragma unroll
    for (int i = 0; i < 16; i += 2) {
      float4 t0 = wr[i];
      float4 t1 = wr[i + 1];
      a0 += (v2f){t0.x, t0.y} * xv[2 * i + 0];   // v_pk_fma_f32
      a1 += (v2f){t0.z, t0.w} * xv[2 * i + 1];
      a2 += (v2f){t1.x, t1.y} * xv[2 * i + 2];
      a3 += (v2f){t1.z, t1.w} * xv[2 * i + 3];
    }
    v2f s01 = a0 + a1;
    v2f s23 = a2 + a3;
    v2f s = s01 + s23;
    float dot = s.x + s.y;
    float ad = sx + se[c];
    float d = fmaf(-2.0f, dot, ad);
    unsigned long long key =
        ((unsigned long long)__float_as_uint(d) << 32) | (unsigned long long)c;
    if (key < best) best = key;
  }
  atomicMin(&keys[row], best);
}

// Phase 3 (grid 256x256, 128 rows/block): decode per-row key -> index, write
// indices (as float), STE quantized output x + fl(w - x), fp64 loss partial
// via wave shuffle reduce -> one atomic per block.
__global__ __launch_bounds__(256) void vq_out(const float* __restrict__ x,
                                              const float* __restrict__ w,
                                              const unsigned long long* __restrict__ keys,
                                              float* __restrict__ outq,
                                              float* __restrict__ outidx,
                                              double* __restrict__ loss) {
  __shared__ int sidx[128];
  __shared__ double part[4];
  const int b = blockIdx.x, t = threadIdx.x;

  if (t < 128) {
    const int row = b * 128 + t;
    unsigned long long k = keys[row];
    const int idx = (int)(unsigned int)(k & 0xFFFFFFFFull);
    outidx[row] = (float)idx;
    sidx[t] = idx;
  }
  __syncthreads();

  double acc = 0.0;
  const float4* x4 = (const float4*)x;
  float4* o4 = (float4*)outq;
#pragma unroll
  for (int i = 0; i < 8; ++i) {
    const int e = i * 256 + t;          // 0..2047 float4s of this block's rows
    const int rl = e >> 4;              // local row (0..127)
    const int d4 = e & 15;              // float4 within the row
    const size_t gofs = ((size_t)b * 128 + rl) * 16 + d4;
    float4 xvv = x4[gofs];
    const float4* wr = (const float4*)(w + (size_t)sidx[rl] * DIM);
    float4 wv = wr[d4];
    float tx = wv.x - xvv.x, ty = wv.y - xvv.y;
    float tz = wv.z - xvv.z, tw = wv.w - xvv.w;
    float4 q;
    q.x = xvv.x + tx; q.y = xvv.y + ty;   // ref STE: x + fl(q - x)
    q.z = xvv.z + tz; q.w = xvv.w + tw;
    o4[gofs] = q;
    acc += (double)tx * tx + (double)ty * ty + (double)tz * tz + (double)tw * tw;
  }

#pragma unroll
  for (int s = 32; s > 0; s >>= 1) acc += __shfl_down(acc, s, 64);
  if ((t & 63) == 0) part[t >> 6] = acc;
  __syncthreads();
  if (t == 0) atomicAdd(loss, (part[0] + part[1]) + (part[2] + part[3]));
}

// Phase 4: commitment = 0.25*(q_loss + e_loss) = 0.5 * mean (q==e numerically)
__global__ void vq_fin(const double* __restrict__ loss, float* __restrict__ outloss) {
  float m = (float)(*loss / (double)NELEM);
  *outloss = 0.5f * m;
}

extern "C" void kernel_launch(void* const* d_in, const int* in_sizes, int n_in,
                              void* d_out, int out_size, void* d_ws, size_t ws_size,
                              hipStream_t stream) {
  const float* x = (const float*)d_in[0];   // inputs (32,64,32,32) fp32
  const float* w = (const float*)d_in[1];   // weight (1024,64) fp32

  float* outq    = (float*)d_out;           // [0, 2097152)
  float* outidx  = outq + NELEM;            // [2097152, +32768)
  float* outloss = outidx + NROWS;          // [2129920]

  char* wsb = (char*)d_ws;
  double* loss = (double*)wsb;                                      // 8 B
  float* se    = (float*)(wsb + 256);                               // 4 KB
  float* sxv   = (float*)(wsb + 8192);                              // 128 KB
  unsigned long long* keys = (unsigned long long*)(wsb + 147456);   // 256 KB

  hipLaunchKernelGGL(vq_prep, dim3(128),  dim3(256), 0, stream, x, w, se, sxv, keys, loss);
  hipLaunchKernelGGL(vq_dist, dim3(1024), dim3(256), 0, stream, x, w, se, sxv, keys);
  hipLaunchKernelGGL(vq_out,  dim3(256),  dim3(256), 0, stream, x, w, keys, outq, outidx, loss);
  hipLaunchKernelGGL(vq_fin,  dim3(1),    dim3(1),   0, stream, loss, outloss);
}